// Round 17
// baseline (576.797 us; speedup 1.0000x reference)
//
#include <hip/hip_runtime.h>
#include <hip/hip_bf16.h>
#include <stdint.h>

#define B_   4
#define C_   256
#define CQK_ 32
#define N_   4096

typedef float f32x4  __attribute__((ext_vector_type(4)));
typedef short bf16x8 __attribute__((ext_vector_type(8)));
typedef unsigned uint4v __attribute__((ext_vector_type(4)));

__device__ __forceinline__ unsigned short f2bf(float f) {
    unsigned u = __builtin_bit_cast(unsigned, f);
    u += 0x7FFFu + ((u >> 16) & 1u);   // RNE
    return (unsigned short)(u >> 16);
}
__device__ __forceinline__ unsigned pack2(float a, float b) {
    return (unsigned)f2bf(a) | ((unsigned)f2bf(b) << 16);
}

// V fragment layout (plain m-order, r7-r15 verified): PV B-frag is lane-linear.
__device__ __forceinline__ size_t vfrag_off(int b, int e, int m) {
    return ((((size_t)b * 128 + (m >> 5)) * 16 + (e >> 4)) * 64
            + (size_t)((m >> 3) & 3) * 16 + (e & 15)) * 8 + (m & 7);
}

// ---------------- W fp32 -> bf16 (standalone, 160KB total) ----------------
__global__ __launch_bounds__(256) void wconv_kernel(
        const float* __restrict__ Wq, const float* __restrict__ Wk,
        const float* __restrict__ Wv,
        unsigned short* __restrict__ Wqb, unsigned short* __restrict__ Wkb,
        unsigned short* __restrict__ Wvb) {
    for (int p = blockIdx.x * 256 + threadIdx.x; p < 40960; p += 64 * 256) {
        const float* s; unsigned short* d; int off;
        if (p < 4096)      { s = Wq; d = Wqb; off = p; }
        else if (p < 8192) { s = Wk; d = Wkb; off = p - 4096; }
        else               { s = Wv; d = Wvb; off = p - 8192; }
        *(unsigned*)(d + off * 2) = pack2(s[off * 2], s[off * 2 + 1]);
    }
}

// ---------------- fused projections (r14/r15-verified) ----------------
__global__ __launch_bounds__(256) void proj_gemm(
        const float* __restrict__ x, const float* __restrict__ y,
        const unsigned short* __restrict__ Wqb, const unsigned short* __restrict__ Wkb,
        const unsigned short* __restrict__ Wvb,
        const float* __restrict__ bq, const float* __restrict__ bk,
        const float* __restrict__ bv,
        unsigned short* __restrict__ qf, unsigned short* __restrict__ kf,
        unsigned short* __restrict__ vf) {
    __shared__ char xlds[64 * 512];
    __shared__ char ylds[64 * 512];
    const int tid = threadIdx.x, w = tid >> 6, l = tid & 63;
    const int lr = l & 15, lg = l >> 4;
    const int gid = blockIdx.x;
    const int b  = (gid >> 1) & 3;
    const int n0 = ((((gid >> 3) << 1) | (gid & 1))) * 64;

    {
        const int j = l & 7;
        const float* spx = x + (size_t)b * C_ * N_ + n0 + l;
        const float* spy = y + (size_t)b * C_ * N_ + n0 + l;
#pragma unroll
        for (int gl = 0; gl < 8; ++gl) {
            const int c8 = w * 64 + gl * 8;
            const int slot = (gl + j) & 7;
            uint4v px, py;
#pragma unroll
            for (int t = 0; t < 4; ++t) {
                px[t] = pack2(spx[(size_t)(c8 + 2 * t) * N_], spx[(size_t)(c8 + 2 * t + 1) * N_]);
                py[t] = pack2(spy[(size_t)(c8 + 2 * t) * N_], spy[(size_t)(c8 + 2 * t + 1) * N_]);
            }
            *(uint4v*)(xlds + l * 512 + w * 128 + slot * 16) = px;
            *(uint4v*)(ylds + l * 512 + w * 128 + slot * 16) = py;
        }
    }
    __syncthreads();

#define AFRAG(LDS, ROW, G)                                                     \
    (*(const bf16x8*)((LDS) + (ROW) * 512 + ((G) >> 3) * 128                   \
                      + ((((G) & 7) + ((ROW) & 7)) & 7) * 16))

    f32x4 accV[4][4];
    f32x4 accQ[4];
#pragma unroll
    for (int e = 0; e < 4; ++e)
#pragma unroll
        for (int m = 0; m < 4; ++m) accV[e][m] = (f32x4){0.f, 0.f, 0.f, 0.f};
#pragma unroll
    for (int m = 0; m < 4; ++m) accQ[m] = (f32x4){0.f, 0.f, 0.f, 0.f};

    const unsigned short* __restrict__ Wqk = (w < 2) ? Wqb : Wkb;
    const int d0 = (w & 1) * 16;

#pragma unroll
    for (int ks = 0; ks < 8; ++ks) {
        const int c0 = ks * 32 + lg * 8;
        const int g  = ks * 4 + lg;
        bf16x8 aY[4], aS[4];
#pragma unroll
        for (int mb = 0; mb < 4; ++mb) aY[mb] = AFRAG(ylds, mb * 16 + lr, g);
        if (w < 2) {
#pragma unroll
            for (int mb = 0; mb < 4; ++mb) aS[mb] = AFRAG(xlds, mb * 16 + lr, g);
        } else {
#pragma unroll
            for (int mb = 0; mb < 4; ++mb) aS[mb] = aY[mb];
        }
        bf16x8 bV[4];
#pragma unroll
        for (int eb = 0; eb < 4; ++eb)
            bV[eb] = *(const bf16x8*)(Wvb + (size_t)(w * 64 + eb * 16 + lr) * C_ + c0);
        const bf16x8 bQ = *(const bf16x8*)(Wqk + (size_t)(d0 + lr) * C_ + c0);
#pragma unroll
        for (int eb = 0; eb < 4; ++eb)
#pragma unroll
            for (int mb = 0; mb < 4; ++mb)
                accV[eb][mb] = __builtin_amdgcn_mfma_f32_16x16x32_bf16(
                    aY[mb], bV[eb], accV[eb][mb], 0, 0, 0);
#pragma unroll
        for (int mb = 0; mb < 4; ++mb)
            accQ[mb] = __builtin_amdgcn_mfma_f32_16x16x32_bf16(aS[mb], bQ, accQ[mb], 0, 0, 0);
    }
#undef AFRAG

#pragma unroll
    for (int eb = 0; eb < 4; ++eb) {
        const int e = w * 64 + eb * 16 + lr;
        const float bve = bv[e];
#pragma unroll
        for (int mb = 0; mb < 4; ++mb) {
            const size_t off = vfrag_off(b, e, n0 + mb * 16 + lg * 4);
            unsigned* p = (unsigned*)(vf + off);
            p[0] = pack2(accV[eb][mb][0] + bve, accV[eb][mb][1] + bve);
            p[1] = pack2(accV[eb][mb][2] + bve, accV[eb][mb][3] + bve);
        }
    }
    const float bqv = ((w < 2) ? bq : bk)[d0 + lr];
    unsigned short* __restrict__ dqk = (w < 2) ? qf : kf;
#pragma unroll
    for (int mb = 0; mb < 4; ++mb)
#pragma unroll
        for (int r = 0; r < 4; ++r) {
            const int n = n0 + mb * 16 + lg * 4 + r;
            dqk[((size_t)b * N_ + n) * CQK_ + d0 + lr] = f2bf(accQ[mb][r] + bqv);
        }
}

// ---------------- fused flash attention: r15 dataflow + LDS union -> 2 blocks/CU ----------------
// TQ=64, TK=128, ks-split PV (verified 53.6us). oslab ALIASES the P arena
// (temporally disjoint: P dead after main loop; __syncthreads separates).
// LDS 102.9KB -> ~67.8KB and VGPR<=128 (__launch_bounds__(512,4)) -> 2 blocks/CU.
__global__ __launch_bounds__(512, 4) void attn_kernel(
        const unsigned short* __restrict__ qf, const unsigned short* __restrict__ kf,
        const unsigned short* __restrict__ vf, const float* __restrict__ x,
        const float* __restrict__ gamma, float* __restrict__ out) {
    __shared__ char arena[2 * 64 * 128 * 4 + 8 * 64 * 4 + 64 * 4];  // 67.8 KB
    char* plds = arena;                              // [2][64*272] = 34816 B (loop only)
    auto oslab = (float (*)[64][128])arena;          // [2][64][128] = 65536 B (post-loop)
    float* cLs = (float*)(arena + 2 * 64 * 128 * 4); // [8][64] (beyond oslab)
    float* cLt = cLs + 8 * 64;
    const int tid = threadIdx.x, w = tid >> 6, l = tid & 63;
    const int lr = l & 15, lg = l >> 4;
    const int gid = blockIdx.x;
    const int b  = (gid >> 1) & 3;                       // batch -> XCD pair
    const int q0 = ((((gid >> 3) << 1) | (gid & 1))) * 64;
    const int eh = w >> 2, ksw = w & 3;

    bf16x8 qfr[4];
#pragma unroll
    for (int qblk = 0; qblk < 4; ++qblk)
        qfr[qblk] = *(const bf16x8*)(
            qf + ((size_t)b * N_ + q0 + qblk * 16 + lr) * CQK_ + lg * 8);

    f32x4 acc[4][8];
#pragma unroll
    for (int i = 0; i < 4; ++i)
#pragma unroll
        for (int j = 0; j < 8; ++j) acc[i][j] = (f32x4){0.f, 0.f, 0.f, 0.f};
    float Lacc[4] = {0.f, 0.f, 0.f, 0.f};

    const unsigned short* kbase = kf + ((size_t)b * N_ + w * 16 + lr) * CQK_ + lg * 8;

#define PREF_K(T, K)                                                           \
    K = *(const bf16x8*)(kbase + (size_t)(((T) & 31) * 128) * CQK_);

#define PREF_V(T)                                                              \
    {                                                                          \
        const int t_ = (T) & 31;                                               \
        _Pragma("unroll")                                                      \
        for (int ebi_ = 0; ebi_ < 8; ++ebi_)                                   \
            vV[ebi_] = *(const bf16x8*)(                                       \
                vf + ((size_t)((b * 128 + t_ * 4 + ksw) * 16 + eh * 8 + ebi_)) \
                         * 512 + l * 8);                                       \
    }

#define BODY(T, K)                                                             \
    {                                                                          \
        f32x4 e4_[4];                                                          \
        _Pragma("unroll")                                                      \
        for (int qblk = 0; qblk < 4; ++qblk)                                   \
            e4_[qblk] = __builtin_amdgcn_mfma_f32_16x16x32_bf16(               \
                K, qfr[qblk], (f32x4){0.f, 0.f, 0.f, 0.f}, 0, 0, 0);           \
        char* pw_ = plds + ((T) & 1) * 17408;                                  \
        const int m2_ = w * 16 + lg * 4;                                       \
        _Pragma("unroll")                                                      \
        for (int qblk = 0; qblk < 4; ++qblk) {                                 \
            const float p0 = __expf(e4_[qblk][0]);                             \
            const float p1 = __expf(e4_[qblk][1]);                             \
            const float p2 = __expf(e4_[qblk][2]);                             \
            const float p3 = __expf(e4_[qblk][3]);                             \
            Lacc[qblk] += (p0 + p1) + (p2 + p3);                               \
            unsigned u0, u1;                                                   \
            asm("v_cvt_pk_bf16_f32 %0, %1, %2" : "=v"(u0) : "v"(p0), "v"(p1)); \
            asm("v_cvt_pk_bf16_f32 %0, %1, %2" : "=v"(u1) : "v"(p2), "v"(p3)); \
            const int q_ = qblk * 16 + lr;                                     \
            const int byte_ = q_ * 272 + ((m2_ >> 3) << 4) + (m2_ & 7) * 2;    \
            *(unsigned long long*)(pw_ + byte_) =                              \
                (unsigned long long)u0 | ((unsigned long long)u1 << 32);       \
        }                                                                      \
        asm volatile("s_waitcnt lgkmcnt(0)" ::: "memory");                     \
        __builtin_amdgcn_s_barrier();                                          \
        asm volatile("" ::: "memory");                                         \
        PREF_K((T) + 2, K);                                                    \
        __builtin_amdgcn_s_setprio(1);                                         \
        _Pragma("unroll")                                                      \
        for (int qblk = 0; qblk < 4; ++qblk) {                                 \
            const int q_ = qblk * 16 + lr;                                     \
            const bf16x8 pa_ = *(const bf16x8*)(                               \
                pw_ + q_ * 272 + ((ksw * 4 + lg) << 4));                       \
            _Pragma("unroll")                                                  \
            for (int ebi_ = 0; ebi_ < 8; ++ebi_)                               \
                acc[qblk][ebi_] = __builtin_amdgcn_mfma_f32_16x16x32_bf16(     \
                    pa_, vV[ebi_], acc[qblk][ebi_], 0, 0, 0);                  \
        }                                                                      \
        __builtin_amdgcn_s_setprio(0);                                         \
        PREF_V((T) + 1);                /* consumed next body after QK+exp */  \
    }

    bf16x8 kA, kB, vV[8];
    PREF_K(0, kA);
    PREF_K(1, kB);
    PREF_V(0);

    for (int kt = 0; kt < 32; kt += 2) {
        BODY(kt, kA);
        BODY(kt + 1, kB);
    }
#undef PREF_K
#undef PREF_V
#undef BODY

    // ---- L reduction ----
#pragma unroll
    for (int qblk = 0; qblk < 4; ++qblk) {
        Lacc[qblk] += __shfl_xor(Lacc[qblk], 16);
        Lacc[qblk] += __shfl_xor(Lacc[qblk], 32);
    }
    if (l < 16) {
#pragma unroll
        for (int qblk = 0; qblk < 4; ++qblk) cLs[w * 64 + qblk * 16 + lr] = Lacc[qblk];
    }
    __syncthreads();
    if (tid < 64) {
        float s = 0.f;
#pragma unroll
        for (int w2 = 0; w2 < 8; ++w2) s += cLs[w2 * 64 + tid];
        cLt[tid] = 1.0f / s;
    }
    __syncthreads();   // P arena dead from here; oslab aliasing begins

    // ---- O reduction: chain ksw 3 -> 2 -> 1 -> 0 through oslab[eh] ----
#pragma unroll
    for (int round = 3; round > 0; --round) {
        if (ksw == round) {
#pragma unroll
            for (int qblk = 0; qblk < 4; ++qblk)
#pragma unroll
                for (int ebi = 0; ebi < 8; ++ebi)
#pragma unroll
                    for (int r = 0; r < 4; ++r)
                        oslab[eh][qblk * 16 + lg * 4 + r][ebi * 16 + lr] = acc[qblk][ebi][r];
        }
        __syncthreads();
        if (ksw == round - 1) {
#pragma unroll
            for (int qblk = 0; qblk < 4; ++qblk)
#pragma unroll
                for (int ebi = 0; ebi < 8; ++ebi)
#pragma unroll
                    for (int r = 0; r < 4; ++r)
                        acc[qblk][ebi][r] += oslab[eh][qblk * 16 + lg * 4 + r][ebi * 16 + lr];
        }
        __syncthreads();
    }
    if (ksw == 0) {
#pragma unroll
        for (int qblk = 0; qblk < 4; ++qblk)
#pragma unroll
            for (int ebi = 0; ebi < 8; ++ebi)
#pragma unroll
                for (int r = 0; r < 4; ++r)
                    oslab[eh][qblk * 16 + lg * 4 + r][ebi * 16 + lr] = acc[qblk][ebi][r];
    }
    __syncthreads();

    // ---- epilogue: each wave stores its e-slice ----
    const float g = gamma[0];
#pragma unroll
    for (int qblk = 0; qblk < 4; ++qblk) {
        float rI[4];
#pragma unroll
        for (int r = 0; r < 4; ++r) rI[r] = cLt[qblk * 16 + lg * 4 + r];
        const int nb = q0 + qblk * 16 + lg * 4;
#pragma unroll
        for (int ebi = 0; ebi < 2; ++ebi) {
            const int e = (w * 2 + ebi) * 16 + lr;
            const size_t idx = ((size_t)b * C_ + e) * N_ + nb;
            const f32x4 xv = *(const f32x4*)(x + idx);
            f32x4 ov;
#pragma unroll
            for (int r = 0; r < 4; ++r) {
                const float val = oslab[e >> 7][qblk * 16 + lg * 4 + r][e & 127];
                ov[r] = g * val * rI[r] + xv[r];
            }
            *(f32x4*)(out + idx) = ov;
        }
    }
}

extern "C" void kernel_launch(void* const* d_in, const int* in_sizes, int n_in,
                              void* d_out, int out_size, void* d_ws, size_t ws_size,
                              hipStream_t stream) {
    (void)in_sizes; (void)n_in; (void)out_size; (void)ws_size;
    const float* x     = (const float*)d_in[0];
    const float* y     = (const float*)d_in[1];
    const float* Wq    = (const float*)d_in[2];
    const float* bq    = (const float*)d_in[3];
    const float* Wk    = (const float*)d_in[4];
    const float* bk    = (const float*)d_in[5];
    const float* Wv    = (const float*)d_in[6];
    const float* bv    = (const float*)d_in[7];
    const float* gamma = (const float*)d_in[8];
    float* out = (float*)d_out;

    unsigned short* qf  = (unsigned short*)d_ws;
    unsigned short* kf  = qf + (size_t)B_ * N_ * CQK_;
    unsigned short* vf  = kf + (size_t)B_ * N_ * CQK_;
    unsigned short* Wqb = vf + (size_t)B_ * N_ * C_;
    unsigned short* Wkb = Wqb + CQK_ * C_;
    unsigned short* Wvb = Wkb + CQK_ * C_;

    wconv_kernel<<<dim3(64), 256, 0, stream>>>(Wq, Wk, Wv, Wqb, Wkb, Wvb);
    proj_gemm<<<dim3(256), 256, 0, stream>>>(x, y, Wqb, Wkb, Wvb, bq, bk, bv, qf, kf, vf);
    attn_kernel<<<dim3(256), 512, 0, stream>>>(qf, kf, vf, x, gamma, out);
}

// Round 18
// 69.925 us; speedup vs baseline: 8.2488x; 8.2488x over previous
//
#include <hip/hip_runtime.h>
#include <hip/hip_bf16.h>
#include <stdint.h>

#define B_   4
#define C_   256
#define CQK_ 32
#define N_   4096

typedef float f32x4  __attribute__((ext_vector_type(4)));
typedef short bf16x8 __attribute__((ext_vector_type(8)));
typedef unsigned uint4v __attribute__((ext_vector_type(4)));

__device__ __forceinline__ unsigned short f2bf(float f) {
    unsigned u = __builtin_bit_cast(unsigned, f);
    u += 0x7FFFu + ((u >> 16) & 1u);   // RNE
    return (unsigned short)(u >> 16);
}
__device__ __forceinline__ unsigned pack2(float a, float b) {
    return (unsigned)f2bf(a) | ((unsigned)f2bf(b) << 16);
}

// V fragment layout (plain m-order, r7-r15 verified): PV B-frag is lane-linear.
__device__ __forceinline__ size_t vfrag_off(int b, int e, int m) {
    return ((((size_t)b * 128 + (m >> 5)) * 16 + (e >> 4)) * 64
            + (size_t)((m >> 3) & 3) * 16 + (e & 15)) * 8 + (m & 7);
}

// ---------------- W fp32 -> bf16 (standalone, 160KB total) ----------------
__global__ __launch_bounds__(256) void wconv_kernel(
        const float* __restrict__ Wq, const float* __restrict__ Wk,
        const float* __restrict__ Wv,
        unsigned short* __restrict__ Wqb, unsigned short* __restrict__ Wkb,
        unsigned short* __restrict__ Wvb) {
    for (int p = blockIdx.x * 256 + threadIdx.x; p < 40960; p += 64 * 256) {
        const float* s; unsigned short* d; int off;
        if (p < 4096)      { s = Wq; d = Wqb; off = p; }
        else if (p < 8192) { s = Wk; d = Wkb; off = p - 4096; }
        else               { s = Wv; d = Wvb; off = p - 8192; }
        *(unsigned*)(d + off * 2) = pack2(s[off * 2], s[off * 2 + 1]);
    }
}

// ---------------- fused projections: fp32 x/y staged in LDS, MFMA body (r14/r15-verified) ----------------
// LDS tile [64 rows=n][256 c] bf16, 512B rows, 16B slots rotated by row: slot=(g+row)&7.
__global__ __launch_bounds__(256) void proj_gemm(
        const float* __restrict__ x, const float* __restrict__ y,
        const unsigned short* __restrict__ Wqb, const unsigned short* __restrict__ Wkb,
        const unsigned short* __restrict__ Wvb,
        const float* __restrict__ bq, const float* __restrict__ bk,
        const float* __restrict__ bv,
        unsigned short* __restrict__ qf, unsigned short* __restrict__ kf,
        unsigned short* __restrict__ vf) {
    __shared__ char xlds[64 * 512];
    __shared__ char ylds[64 * 512];
    const int tid = threadIdx.x, w = tid >> 6, l = tid & 63;
    const int lr = l & 15, lg = l >> 4;
    const int gid = blockIdx.x;
    const int b  = (gid >> 1) & 3;
    const int n0 = ((((gid >> 3) << 1) | (gid & 1))) * 64;

    // ---- stage: thread = pixel row l; wave covers c-chunk w*64..+63 ----
    {
        const int j = l & 7;
        const float* spx = x + (size_t)b * C_ * N_ + n0 + l;
        const float* spy = y + (size_t)b * C_ * N_ + n0 + l;
#pragma unroll
        for (int gl = 0; gl < 8; ++gl) {
            const int c8 = w * 64 + gl * 8;
            const int slot = (gl + j) & 7;
            uint4v px, py;
#pragma unroll
            for (int t = 0; t < 4; ++t) {
                px[t] = pack2(spx[(size_t)(c8 + 2 * t) * N_], spx[(size_t)(c8 + 2 * t + 1) * N_]);
                py[t] = pack2(spy[(size_t)(c8 + 2 * t) * N_], spy[(size_t)(c8 + 2 * t + 1) * N_]);
            }
            *(uint4v*)(xlds + l * 512 + w * 128 + slot * 16) = px;
            *(uint4v*)(ylds + l * 512 + w * 128 + slot * 16) = py;
        }
    }
    __syncthreads();

#define AFRAG(LDS, ROW, G)                                                     \
    (*(const bf16x8*)((LDS) + (ROW) * 512 + ((G) >> 3) * 128                   \
                      + ((((G) & 7) + ((ROW) & 7)) & 7) * 16))

    f32x4 accV[4][4];
    f32x4 accQ[4];
#pragma unroll
    for (int e = 0; e < 4; ++e)
#pragma unroll
        for (int m = 0; m < 4; ++m) accV[e][m] = (f32x4){0.f, 0.f, 0.f, 0.f};
#pragma unroll
    for (int m = 0; m < 4; ++m) accQ[m] = (f32x4){0.f, 0.f, 0.f, 0.f};

    const unsigned short* __restrict__ Wqk = (w < 2) ? Wqb : Wkb;
    const int d0 = (w & 1) * 16;

#pragma unroll
    for (int ks = 0; ks < 8; ++ks) {
        const int c0 = ks * 32 + lg * 8;
        const int g  = ks * 4 + lg;
        bf16x8 aY[4], aS[4];
#pragma unroll
        for (int mb = 0; mb < 4; ++mb) aY[mb] = AFRAG(ylds, mb * 16 + lr, g);
        if (w < 2) {
#pragma unroll
            for (int mb = 0; mb < 4; ++mb) aS[mb] = AFRAG(xlds, mb * 16 + lr, g);
        } else {
#pragma unroll
            for (int mb = 0; mb < 4; ++mb) aS[mb] = aY[mb];
        }
        bf16x8 bV[4];
#pragma unroll
        for (int eb = 0; eb < 4; ++eb)
            bV[eb] = *(const bf16x8*)(Wvb + (size_t)(w * 64 + eb * 16 + lr) * C_ + c0);
        const bf16x8 bQ = *(const bf16x8*)(Wqk + (size_t)(d0 + lr) * C_ + c0);
#pragma unroll
        for (int eb = 0; eb < 4; ++eb)
#pragma unroll
            for (int mb = 0; mb < 4; ++mb)
                accV[eb][mb] = __builtin_amdgcn_mfma_f32_16x16x32_bf16(
                    aY[mb], bV[eb], accV[eb][mb], 0, 0, 0);
#pragma unroll
        for (int mb = 0; mb < 4; ++mb)
            accQ[mb] = __builtin_amdgcn_mfma_f32_16x16x32_bf16(aS[mb], bQ, accQ[mb], 0, 0, 0);
    }
#undef AFRAG

    // V epilogue (verbatim r13)
#pragma unroll
    for (int eb = 0; eb < 4; ++eb) {
        const int e = w * 64 + eb * 16 + lr;
        const float bve = bv[e];
#pragma unroll
        for (int mb = 0; mb < 4; ++mb) {
            const size_t off = vfrag_off(b, e, n0 + mb * 16 + lg * 4);
            unsigned* p = (unsigned*)(vf + off);
            p[0] = pack2(accV[eb][mb][0] + bve, accV[eb][mb][1] + bve);
            p[1] = pack2(accV[eb][mb][2] + bve, accV[eb][mb][3] + bve);
        }
    }
    const float bqv = ((w < 2) ? bq : bk)[d0 + lr];
    unsigned short* __restrict__ dqk = (w < 2) ? qf : kf;
#pragma unroll
    for (int mb = 0; mb < 4; ++mb)
#pragma unroll
        for (int r = 0; r < 4; ++r) {
            const int n = n0 + mb * 16 + lg * 4 + r;
            dqk[((size_t)b * N_ + n) * CQK_ + d0 + lr] = f2bf(accQ[mb][r] + bqv);
        }
}

// ---------------- fused flash attention: r13/r15 VERBATIM (53.6us verified, no spill) ----------------
// TQ=64, TK=128, ks-split PV: wave (eh=w>>2, ks=w&3), partial O over its m-quarter,
// 4 P-reads/tile, V-dup=1, single register-prefetched V set. End: O-reduction via LDS.
__global__ __launch_bounds__(512, 2) void attn_kernel(
        const unsigned short* __restrict__ qf, const unsigned short* __restrict__ kf,
        const unsigned short* __restrict__ vf, const float* __restrict__ x,
        const float* __restrict__ gamma, float* __restrict__ out) {
    __shared__ char plds[2][64 * 272];      // P: [64q][128m] bf16, 272B row stride
    __shared__ float oslab[2][64][128];     // O-reduction slabs (per e-half)
    __shared__ float cLs[8][64];
    __shared__ float cLt[64];
    const int tid = threadIdx.x, w = tid >> 6, l = tid & 63;
    const int lr = l & 15, lg = l >> 4;
    const int gid = blockIdx.x;
    const int b  = (gid >> 1) & 3;                       // batch -> XCD pair
    const int q0 = ((((gid >> 3) << 1) | (gid & 1))) * 64;
    const int eh = w >> 2, ksw = w & 3;

    bf16x8 qfr[4];
#pragma unroll
    for (int qblk = 0; qblk < 4; ++qblk)
        qfr[qblk] = *(const bf16x8*)(
            qf + ((size_t)b * N_ + q0 + qblk * 16 + lr) * CQK_ + lg * 8);

    f32x4 acc[4][8];
#pragma unroll
    for (int i = 0; i < 4; ++i)
#pragma unroll
        for (int j = 0; j < 8; ++j) acc[i][j] = (f32x4){0.f, 0.f, 0.f, 0.f};
    float Lacc[4] = {0.f, 0.f, 0.f, 0.f};

    const unsigned short* kbase = kf + ((size_t)b * N_ + w * 16 + lr) * CQK_ + lg * 8;

#define PREF_K(T, K)                                                           \
    K = *(const bf16x8*)(kbase + (size_t)(((T) & 31) * 128) * CQK_);

#define PREF_V(T)                                                              \
    {                                                                          \
        const int t_ = (T) & 31;                                               \
        _Pragma("unroll")                                                      \
        for (int ebi_ = 0; ebi_ < 8; ++ebi_)                                   \
            vV[ebi_] = *(const bf16x8*)(                                       \
                vf + ((size_t)((b * 128 + t_ * 4 + ksw) * 16 + eh * 8 + ebi_)) \
                         * 512 + l * 8);                                       \
    }

#define BODY(T, K)                                                             \
    {                                                                          \
        f32x4 e4_[4];                                                          \
        _Pragma("unroll")                                                      \
        for (int qblk = 0; qblk < 4; ++qblk)                                   \
            e4_[qblk] = __builtin_amdgcn_mfma_f32_16x16x32_bf16(               \
                K, qfr[qblk], (f32x4){0.f, 0.f, 0.f, 0.f}, 0, 0, 0);           \
        char* pw_ = plds[(T) & 1];                                             \
        const int m2_ = w * 16 + lg * 4;                                       \
        _Pragma("unroll")                                                      \
        for (int qblk = 0; qblk < 4; ++qblk) {                                 \
            const float p0 = __expf(e4_[qblk][0]);                             \
            const float p1 = __expf(e4_[qblk][1]);                             \
            const float p2 = __expf(e4_[qblk][2]);                             \
            const float p3 = __expf(e4_[qblk][3]);                             \
            Lacc[qblk] += (p0 + p1) + (p2 + p3);                               \
            unsigned u0, u1;                                                   \
            asm("v_cvt_pk_bf16_f32 %0, %1, %2" : "=v"(u0) : "v"(p0), "v"(p1)); \
            asm("v_cvt_pk_bf16_f32 %0, %1, %2" : "=v"(u1) : "v"(p2), "v"(p3)); \
            const int q_ = qblk * 16 + lr;                                     \
            const int byte_ = q_ * 272 + ((m2_ >> 3) << 4) + (m2_ & 7) * 2;    \
            *(unsigned long long*)(pw_ + byte_) =                              \
                (unsigned long long)u0 | ((unsigned long long)u1 << 32);       \
        }                                                                      \
        asm volatile("s_waitcnt lgkmcnt(0)" ::: "memory");                     \
        __builtin_amdgcn_s_barrier();                                          \
        asm volatile("" ::: "memory");                                         \
        PREF_K((T) + 2, K);                                                    \
        __builtin_amdgcn_s_setprio(1);                                         \
        _Pragma("unroll")                                                      \
        for (int qblk = 0; qblk < 4; ++qblk) {                                 \
            const int q_ = qblk * 16 + lr;                                     \
            const bf16x8 pa_ = *(const bf16x8*)(                               \
                pw_ + q_ * 272 + ((ksw * 4 + lg) << 4));                       \
            _Pragma("unroll")                                                  \
            for (int ebi_ = 0; ebi_ < 8; ++ebi_)                               \
                acc[qblk][ebi_] = __builtin_amdgcn_mfma_f32_16x16x32_bf16(     \
                    pa_, vV[ebi_], acc[qblk][ebi_], 0, 0, 0);                  \
        }                                                                      \
        __builtin_amdgcn_s_setprio(0);                                         \
        PREF_V((T) + 1);                /* consumed next body after QK+exp */  \
    }

    bf16x8 kA, kB, vV[8];
    PREF_K(0, kA);
    PREF_K(1, kB);
    PREF_V(0);

    for (int kt = 0; kt < 32; kt += 2) {
        BODY(kt, kA);
        BODY(kt + 1, kB);
    }
#undef PREF_K
#undef PREF_V
#undef BODY

    // ---- L reduction ----
#pragma unroll
    for (int qblk = 0; qblk < 4; ++qblk) {
        Lacc[qblk] += __shfl_xor(Lacc[qblk], 16);
        Lacc[qblk] += __shfl_xor(Lacc[qblk], 32);
    }
    if (l < 16) {
#pragma unroll
        for (int qblk = 0; qblk < 4; ++qblk) cLs[w][qblk * 16 + lr] = Lacc[qblk];
    }
    __syncthreads();
    if (tid < 64) {
        float s = 0.f;
#pragma unroll
        for (int w2 = 0; w2 < 8; ++w2) s += cLs[w2][tid];
        cLt[tid] = 1.0f / s;
    }
    __syncthreads();

    // ---- O reduction: chain ksw 3 -> 2 -> 1 -> 0 through oslab[eh] ----
#pragma unroll
    for (int round = 3; round > 0; --round) {
        if (ksw == round) {
#pragma unroll
            for (int qblk = 0; qblk < 4; ++qblk)
#pragma unroll
                for (int ebi = 0; ebi < 8; ++ebi)
#pragma unroll
                    for (int r = 0; r < 4; ++r)
                        oslab[eh][qblk * 16 + lg * 4 + r][ebi * 16 + lr] = acc[qblk][ebi][r];
        }
        __syncthreads();
        if (ksw == round - 1) {
#pragma unroll
            for (int qblk = 0; qblk < 4; ++qblk)
#pragma unroll
                for (int ebi = 0; ebi < 8; ++ebi)
#pragma unroll
                    for (int r = 0; r < 4; ++r)
                        acc[qblk][ebi][r] += oslab[eh][qblk * 16 + lg * 4 + r][ebi * 16 + lr];
        }
        __syncthreads();
    }
    if (ksw == 0) {
#pragma unroll
        for (int qblk = 0; qblk < 4; ++qblk)
#pragma unroll
            for (int ebi = 0; ebi < 8; ++ebi)
#pragma unroll
                for (int r = 0; r < 4; ++r)
                    oslab[eh][qblk * 16 + lg * 4 + r][ebi * 16 + lr] = acc[qblk][ebi][r];
    }
    __syncthreads();

    // ---- epilogue: each wave stores its e-slice ----
    const float g = gamma[0];
#pragma unroll
    for (int qblk = 0; qblk < 4; ++qblk) {
        float rI[4];
#pragma unroll
        for (int r = 0; r < 4; ++r) rI[r] = cLt[qblk * 16 + lg * 4 + r];
        const int nb = q0 + qblk * 16 + lg * 4;
#pragma unroll
        for (int ebi = 0; ebi < 2; ++ebi) {
            const int e = (w * 2 + ebi) * 16 + lr;
            const size_t idx = ((size_t)b * C_ + e) * N_ + nb;
            const f32x4 xv = *(const f32x4*)(x + idx);
            f32x4 ov;
#pragma unroll
            for (int r = 0; r < 4; ++r) {
                const float val = oslab[e >> 7][qblk * 16 + lg * 4 + r][e & 127];
                ov[r] = g * val * rI[r] + xv[r];
            }
            *(f32x4*)(out + idx) = ov;
        }
    }
}

extern "C" void kernel_launch(void* const* d_in, const int* in_sizes, int n_in,
                              void* d_out, int out_size, void* d_ws, size_t ws_size,
                              hipStream_t stream) {
    (void)in_sizes; (void)n_in; (void)out_size; (void)ws_size;
    const float* x     = (const float*)d_in[0];
    const float* y     = (const float*)d_in[1];
    const float* Wq    = (const float*)d_in[2];
    const float* bq    = (const float*)d_in[3];
    const float* Wk    = (const float*)d_in[4];
    const float* bk    = (const float*)d_in[5];
    const float* Wv    = (const float*)d_in[6];
    const float* bv    = (const float*)d_in[7];
    const float* gamma = (const float*)d_in[8];
    float* out = (float*)d_out;

    unsigned short* qf  = (unsigned short*)d_ws;
    unsigned short* kf  = qf + (size_t)B_ * N_ * CQK_;
    unsigned short* vf  = kf + (size_t)B_ * N_ * CQK_;
    unsigned short* Wqb = vf + (size_t)B_ * N_ * C_;
    unsigned short* Wkb = Wqb + CQK_ * C_;
    unsigned short* Wvb = Wkb + CQK_ * C_;

    wconv_kernel<<<dim3(64), 256, 0, stream>>>(Wq, Wk, Wv, Wqb, Wkb, Wvb);
    proj_gemm<<<dim3(256), 256, 0, stream>>>(x, y, Wqb, Wkb, Wvb, bq, bk, bv, qf, kf, vf);
    attn_kernel<<<dim3(256), 512, 0, stream>>>(qf, kf, vf, x, gamma, out);
}